// Round 6
// baseline (1032.890 us; speedup 1.0000x reference)
//
#include <hip/hip_runtime.h>
#include <stdint.h>

typedef short bf8 __attribute__((ext_vector_type(8)));   // 8 bf16 (4 VGPRs)
typedef float f4  __attribute__((ext_vector_type(4)));   // MFMA acc
typedef unsigned short u16;
typedef unsigned long long u64;

#define LOG2E 1.4426950408889634f

__device__ __forceinline__ u16 f2bf(float f){
  uint32_t u = __builtin_bit_cast(uint32_t, f);
  u += 0x7fffu + ((u >> 16) & 1u);
  return (u16)(u >> 16);
}
// sigmoid of value pre-scaled by log2e: 1/(1+2^-a)
__device__ __forceinline__ float sigm_ps(float a){
  return __builtin_amdgcn_rcpf(1.0f + __builtin_amdgcn_exp2f(-a));
}
// LDS-only barrier: don't drain vmcnt (global stores/loads stay in flight)
__device__ __forceinline__ void bar_lds(){
  asm volatile("s_waitcnt lgkmcnt(0)\n\ts_barrier" ::: "memory");
}

// ---------------------------------------------------------------------------
// Prep: prescaled bf16 weights W0c[512][160]=[Whh0|Wih0|0], W1c[512][256]=
// [Whh1|Wih1]; rows scaled log2e (i,f,o) / 2*log2e (g); prescaled biases.
// ---------------------------------------------------------------------------
__global__ void prep_kernel(const float* __restrict__ Wih0, const float* __restrict__ Whh0,
                            const float* __restrict__ bih0, const float* __restrict__ bhh0,
                            const float* __restrict__ Wih1, const float* __restrict__ Whh1,
                            const float* __restrict__ bih1, const float* __restrict__ bhh1,
                            u16* __restrict__ W0c, u16* __restrict__ W1c,
                            float* __restrict__ bias0, float* __restrict__ bias1){
  int g = blockIdx.x;      // gate row 0..511
  int t = threadIdx.x;     // 0..63
  float s = (g >= 256 && g < 384) ? 2.0f * LOG2E : LOG2E;
  for(int k = t; k < 160; k += 64){
    float v = 0.0f;
    if(k < 128)      v = Whh0[g*128 + k];
    else if(k < 146) v = Wih0[g*18 + (k-128)];
    W0c[g*160 + k] = f2bf(v * s);
  }
  for(int k = t; k < 256; k += 64){
    float v = (k < 128) ? Whh1[g*128 + k] : Wih1[g*128 + (k-128)];
    W1c[g*256 + k] = f2bf(v * s);
  }
  if(t == 0){
    bias0[g] = (bih0[g] + bhh0[g]) * s;
    bias1[g] = (bih1[g] + bhh1[g]) * s;
  }
}

// ===========================================================================
// Shared geometry (both layer kernels), gate-major MFMA:
//   A = prescaled weights (static VGPR frags), M = 16-gate tile
//   B = state/input (N = 16 batch rows), from LDS (recurrent part) or
//       registers (feed-forward part)
// Wave w owns gate tiles {q*128+16w : q=0..3}; lane (quad=lane>>4, l15):
//   acc[q][r] = gate q, comp j=16w+quad*4+r, row l15  (verified R4/R5).
// LDS layout hbT[buf][kc][row][8]: k-slot k of row r lives at
//   [k>>3][r][k&7]  ->  B-frag for kt,quad = &hbT[buf][kt*4+quad][l15][0]
//   addr/4 = kc*64 + row*4 + i  ->  conflict-free (banks tile 0..31).
// ===========================================================================

// ---------------------------------------------------------------------------
// Layer 0: K=160 = [h0(128) | x(18) | 0(14)], KT=5. 32 blocks x 512 thr,
// block owns rows rb*16..+16 for all T. Writes h1[t][row][comp] bf16.
// ---------------------------------------------------------------------------
__global__ __launch_bounds__(512, 2)
void lstm_l0(const u16* __restrict__ Wc, const float* __restrict__ bias,
             const float* __restrict__ xin,   // (512,512,18) f32
             u16* __restrict__ h1out)         // [512 t][512 row][128] bf16
{
  __shared__ __align__(16) u16 hbT[2][20][16][8];  // 20 kc = h(16) + x(4)

  const int tid  = threadIdx.x;
  const int wave = tid >> 6;
  const int lane = tid & 63;
  const int quad = lane >> 4;
  const int l15  = lane & 15;
  const int rowbase = blockIdx.x * 16;

  // static weight A-frags: lane (l15,quad) holds W[(q*128+16w+l15)][kt*32+quad*8 ..+8]
  bf8 A[4][5];
#pragma unroll
  for(int q = 0; q < 4; q++){
    const u16* wp = Wc + (u64)(128*q + 16*wave + l15)*160 + quad*8;
#pragma unroll
    for(int kt = 0; kt < 5; kt++) A[q][kt] = *(const bf8*)(wp + kt*32);
  }
  f4 bini[4];
#pragma unroll
  for(int q = 0; q < 4; q++) bini[q] = *(const f4*)(bias + 128*q + 16*wave + quad*4);
  float c[4] = {0.f,0.f,0.f,0.f};

  // zero both buffers (h(0)=0; x pad slots stay 0 forever)
  for(int i = tid; i < 2*20*16*8; i += 512) ((u16*)hbT)[i] = 0;
  __syncthreads();
  // stage x(0) into buf0: slot 128+k -> kc=16+(k>>3), e=k&7
  int sr = 0, sk = 0;
  if(tid < 288){ sr = tid/18; sk = tid - 18*sr; }
  if(tid < 288)
    hbT[0][16+(sk>>3)][sr][sk&7] = f2bf(xin[((u64)(rowbase+sr)*512)*18 + sk]);
  __syncthreads();

  for(int t = 0; t < 512; t++){
    const int cur = t & 1, nxt = cur ^ 1;
    // prefetch x(t+1)
    float xv = 0.f;
    if(tid < 288 && t < 511)
      xv = xin[((u64)(rowbase+sr)*512 + (t+1))*18 + sk];

    bf8 B[5];
#pragma unroll
    for(int kt = 0; kt < 5; kt++) B[kt] = *(const bf8*)&hbT[cur][kt*4+quad][l15][0];

    f4 acc[4];
#pragma unroll
    for(int q = 0; q < 4; q++) acc[q] = bini[q];
#pragma unroll
    for(int kt = 0; kt < 5; kt++){
#pragma unroll
      for(int q = 0; q < 4; q++)
        acc[q] = __builtin_amdgcn_mfma_f32_16x16x32_bf16(A[q][kt], B[kt], acc[q], 0,0,0);
    }

    // in-register cell update: comps j=16w+quad*4+r, row l15
    u64 hpack; u16* hp = (u16*)&hpack;
#pragma unroll
    for(int r = 0; r < 4; r++){
      float ig = sigm_ps(acc[0][r]);
      float fg = sigm_ps(acc[1][r]);
      float gg = 2.f*sigm_ps(acc[2][r]) - 1.f;
      float og = sigm_ps(acc[3][r]);
      c[r] = fg*c[r] + ig*gg;
      float th = 2.f*sigm_ps(c[r]*(2.f*LOG2E)) - 1.f;
      hp[r] = f2bf(og*th);
    }
    // h(t+1) -> next buffer: j=16w+4q+r -> kc=2w+(q>>1), e=4*(q&1)+r
    *(u64*)&hbT[nxt][2*wave + (quad>>1)][l15][4*(quad&1)] = hpack;
    // h1(t) -> global (plain store; completion not needed until kernel end)
    *(u64*)(h1out + ((u64)t*512 + rowbase + l15)*128 + 16*wave + 4*quad) = hpack;
    // x(t+1) -> next buffer
    if(tid < 288 && t < 511) hbT[nxt][16+(sk>>3)][sr][sk&7] = f2bf(xv);
    bar_lds();
  }
}

// ---------------------------------------------------------------------------
// Layer 1: K=256 = [h2(128) | h1(128)], KT=8. 32 blocks x 512 thr.
// h2 (recurrent) through LDS; h1 (feed-forward) straight to B-frag registers,
// prefetched one step ahead. Fused FC head.
// ---------------------------------------------------------------------------
__global__ __launch_bounds__(512, 2)
void lstm_l1(const u16* __restrict__ Wc, const float* __restrict__ bias,
             const u16* __restrict__ h1in,    // [512 t][512 row][128] bf16
             const float* __restrict__ Wfc1, const float* __restrict__ bfc1,
             const float* __restrict__ Wfc2, const float* __restrict__ bfc2,
             float* __restrict__ out)         // (512,) f32
{
  __shared__ __align__(16) u16  hbT[2][16][16][8];  // h2 only
  __shared__ __align__(16) float ffin[16][132];     // final h2 f32 for FC head

  const int tid  = threadIdx.x;
  const int wave = tid >> 6;
  const int lane = tid & 63;
  const int quad = lane >> 4;
  const int l15  = lane & 15;
  const int rowbase = blockIdx.x * 16;

  bf8 A[4][8];
#pragma unroll
  for(int q = 0; q < 4; q++){
    const u16* wp = Wc + (u64)(128*q + 16*wave + l15)*256 + quad*8;
#pragma unroll
    for(int kt = 0; kt < 8; kt++) A[q][kt] = *(const bf8*)(wp + kt*32);
  }
  f4 bini[4];
#pragma unroll
  for(int q = 0; q < 4; q++) bini[q] = *(const f4*)(bias + 128*q + 16*wave + quad*4);
  float c[4] = {0.f,0.f,0.f,0.f};

  for(int i = tid; i < 2*16*16*8; i += 512) ((u16*)hbT)[i] = 0;

  // h1 B-frags for t=0: lane (l15,quad) reads h1[row l15][kh*32+quad*8 ..+8]
  const u16* h1p = h1in + ((u64)rowbase + l15)*128 + 8*quad;
  bf8 h1f[4];
#pragma unroll
  for(int kh = 0; kh < 4; kh++)
    h1f[kh] = *(const bf8*)(h1p + (u64)0*512*128 + 32*kh);
  __syncthreads();

  float hv[4];
  for(int t = 0; t < 512; t++){
    const int cur = t & 1, nxt = cur ^ 1;
    // prefetch h1(t+1) frags into registers
    bf8 h1n[4];
    if(t < 511){
#pragma unroll
      for(int kh = 0; kh < 4; kh++)
        h1n[kh] = *(const bf8*)(h1p + ((u64)(t+1))*512*128 + 32*kh);
    }

    bf8 B[4];
#pragma unroll
    for(int kt = 0; kt < 4; kt++) B[kt] = *(const bf8*)&hbT[cur][kt*4+quad][l15][0];

    f4 acc[4];
#pragma unroll
    for(int q = 0; q < 4; q++) acc[q] = bini[q];
#pragma unroll
    for(int kt = 0; kt < 4; kt++){
#pragma unroll
      for(int q = 0; q < 4; q++)
        acc[q] = __builtin_amdgcn_mfma_f32_16x16x32_bf16(A[q][kt], B[kt], acc[q], 0,0,0);
    }
#pragma unroll
    for(int kh = 0; kh < 4; kh++){
#pragma unroll
      for(int q = 0; q < 4; q++)
        acc[q] = __builtin_amdgcn_mfma_f32_16x16x32_bf16(A[q][4+kh], h1f[kh], acc[q], 0,0,0);
    }

    u64 hpack; u16* hp = (u16*)&hpack;
#pragma unroll
    for(int r = 0; r < 4; r++){
      float ig = sigm_ps(acc[0][r]);
      float fg = sigm_ps(acc[1][r]);
      float gg = 2.f*sigm_ps(acc[2][r]) - 1.f;
      float og = sigm_ps(acc[3][r]);
      c[r] = fg*c[r] + ig*gg;
      float th = 2.f*sigm_ps(c[r]*(2.f*LOG2E)) - 1.f;
      hv[r] = og*th;
      hp[r] = f2bf(hv[r]);
    }
    *(u64*)&hbT[nxt][2*wave + (quad>>1)][l15][4*(quad&1)] = hpack;
    bar_lds();
    if(t < 511){
#pragma unroll
      for(int kh = 0; kh < 4; kh++) h1f[kh] = h1n[kh];
    }
  }

  // stash final h2 (f32) for FC head
#pragma unroll
  for(int r = 0; r < 4; r++) ffin[l15][16*wave + quad*4 + r] = hv[r];
  __syncthreads();

  // FC head: row r = tid>>5, 32 threads x 2 hidden units each
  {
    int r = tid >> 5, u = tid & 31;
    float s0 = bfc1[2*u], s1 = bfc1[2*u+1];
    const float* w0 = Wfc1 + (2*u)*128;
    const float* w1 = Wfc1 + (2*u+1)*128;
    for(int j = 0; j < 128; j++){
      float h = ffin[r][j];
      s0 = fmaf(w0[j], h, s0);
      s1 = fmaf(w1[j], h, s1);
    }
    float term = fmaxf(s0, 0.f)*Wfc2[2*u] + fmaxf(s1, 0.f)*Wfc2[2*u+1];
#pragma unroll
    for(int off = 16; off > 0; off >>= 1) term += __shfl_down(term, off, 32);
    if(u == 0) out[rowbase + r] = sigm_ps((term + bfc2[0]) * LOG2E);
  }
}

// ---------------------------------------------------------------------------
extern "C" void kernel_launch(void* const* d_in, const int* in_sizes, int n_in,
                              void* d_out, int out_size, void* d_ws, size_t ws_size,
                              hipStream_t stream){
  const float* x    = (const float*)d_in[0];
  const float* Wih0 = (const float*)d_in[1];
  const float* Whh0 = (const float*)d_in[2];
  const float* bih0 = (const float*)d_in[3];
  const float* bhh0 = (const float*)d_in[4];
  const float* Wih1 = (const float*)d_in[5];
  const float* Whh1 = (const float*)d_in[6];
  const float* bih1 = (const float*)d_in[7];
  const float* bhh1 = (const float*)d_in[8];
  const float* Wfc1 = (const float*)d_in[9];
  const float* bfc1 = (const float*)d_in[10];
  const float* Wfc2 = (const float*)d_in[11];
  const float* bfc2 = (const float*)d_in[12];

  char* ws = (char*)d_ws;
  u16*   W0c   = (u16*)(ws);                       // 512*160*2 = 163840 B
  u16*   W1c   = (u16*)(ws + 163840);              // 512*256*2 = 262144 B
  float* bias0 = (float*)(ws + 163840 + 262144);   // 2048 B
  float* bias1 = bias0 + 512;                      // 2048 B
  u16*   h1g   = (u16*)(ws + 163840 + 262144 + 4096); // 64 MiB

  prep_kernel<<<dim3(512), dim3(64), 0, stream>>>(Wih0, Whh0, bih0, bhh0,
                                                  Wih1, Whh1, bih1, bhh1,
                                                  W0c, W1c, bias0, bias1);

  lstm_l0<<<dim3(32), dim3(512), 0, stream>>>(W0c, bias0, x, h1g);

  lstm_l1<<<dim3(32), dim3(512), 0, stream>>>(W1c, bias1, h1g,
                                              Wfc1, bfc1, Wfc2, bfc2,
                                              (float*)d_out);
}

// Round 7
// 959.349 us; speedup vs baseline: 1.0767x; 1.0767x over previous
//
#include <hip/hip_runtime.h>
#include <stdint.h>

typedef short bf8 __attribute__((ext_vector_type(8)));   // 8 bf16 (4 VGPRs)
typedef float f4  __attribute__((ext_vector_type(4)));   // MFMA acc
typedef unsigned short u16;
typedef unsigned int   u32;
typedef unsigned long long u64;

#define LOG2E 1.4426950408889634f

__device__ __forceinline__ u16 f2bf(float f){
  uint32_t u = __builtin_bit_cast(uint32_t, f);
  u += 0x7fffu + ((u >> 16) & 1u);
  return (u16)(u >> 16);
}
// sigmoid of value pre-scaled by log2e: 1/(1+2^-a)
__device__ __forceinline__ float sigm_ps(float a){
  return __builtin_amdgcn_rcpf(1.0f + __builtin_amdgcn_exp2f(-a));
}
// LDS-only barrier: don't drain vmcnt (global loads/stores stay in flight)
__device__ __forceinline__ void bar_lds(){
  asm volatile("s_waitcnt lgkmcnt(0)\n\ts_barrier" ::: "memory");
}

// ---------------------------------------------------------------------------
// Prep: prescaled bf16 weights W0c[512][160]=[Whh0|Wih0|0], W1c[512][256]=
// [Whh1|Wih1]; rows scaled log2e (i,f,o) / 2*log2e (g); prescaled biases.
// ---------------------------------------------------------------------------
__global__ void prep_kernel(const float* __restrict__ Wih0, const float* __restrict__ Whh0,
                            const float* __restrict__ bih0, const float* __restrict__ bhh0,
                            const float* __restrict__ Wih1, const float* __restrict__ Whh1,
                            const float* __restrict__ bih1, const float* __restrict__ bhh1,
                            u16* __restrict__ W0c, u16* __restrict__ W1c,
                            float* __restrict__ bias0, float* __restrict__ bias1){
  int g = blockIdx.x;      // gate row 0..511
  int t = threadIdx.x;     // 0..63
  float s = (g >= 256 && g < 384) ? 2.0f * LOG2E : LOG2E;
  for(int k = t; k < 160; k += 64){
    float v = 0.0f;
    if(k < 128)      v = Whh0[g*128 + k];
    else if(k < 146) v = Wih0[g*18 + (k-128)];
    W0c[g*160 + k] = f2bf(v * s);
  }
  for(int k = t; k < 256; k += 64){
    float v = (k < 128) ? Whh1[g*128 + k] : Wih1[g*128 + (k-128)];
    W1c[g*256 + k] = f2bf(v * s);
  }
  if(t == 0){
    bias0[g] = (bih0[g] + bhh0[g]) * s;
    bias1[g] = (bih1[g] + bhh1[g]) * s;
  }
}

// ===========================================================================
// Geometry: 64 blocks x 512 thr, 8 batch rows per block. Gate-major MFMA:
// A = weights (static VGPR frags, M=16-gate tile), B = state (N=16, rows
// 8..15 duplicate 0..7 -> D cols 8..15 garbage, ignored).
// Wave w owns comps [16w,16w+16) for all 4 gate types q. D: col(batch row)
// = lane&15, m(gate) = quad*4+reg.
// Compacted update: lanes l15>=8 take acc[q][2..3] from lane-8 via __shfl;
// every lane then owns exactly 2 (comp,row) updates -> 20 trans instr/wave
// instead of 40. Ownership static across t (c-state in regs).
// LDS hbT[buf][kc][8 rows][8]: slot k of row r at [k>>3][r][k&7];
// B-frag = &hbT[cur][kt*4+quad][l15&7][0]  (conflict-free).
// ===========================================================================

template<bool UP>
__device__ __forceinline__ void cell2(const float g0[4], const float g1[4],
                                      float& c0, float& c1, float& hv0, float& hv1){
  float i0 = sigm_ps(g0[0]), f0 = sigm_ps(g0[1]);
  float G0 = 2.f*sigm_ps(g0[2]) - 1.f;
  float o0 = sigm_ps(g0[3]);
  c0 = f0*c0 + i0*G0;
  hv0 = o0 * (2.f*sigm_ps(c0*(2.f*LOG2E)) - 1.f);
  float i1 = sigm_ps(g1[0]), f1 = sigm_ps(g1[1]);
  float G1 = 2.f*sigm_ps(g1[2]) - 1.f;
  float o1 = sigm_ps(g1[3]);
  c1 = f1*c1 + i1*G1;
  hv1 = o1 * (2.f*sigm_ps(c1*(2.f*LOG2E)) - 1.f);
}

// ---------------------------------------------------------------------------
// Layer 0: K=160 = [h0(128) | x(18) | 0(14)], KT=5. Writes h1[t][row][128].
// ---------------------------------------------------------------------------
__global__ __launch_bounds__(512, 2)
void lstm_l0(const u16* __restrict__ Wc, const float* __restrict__ bias,
             const float* __restrict__ xin,   // (512,512,18) f32
             u16* __restrict__ h1out)         // [512 t][512 row][128] bf16
{
  __shared__ __align__(16) u16 hbT[2][20][8][8];  // 20 kc = h(16) + x(4)

  const int tid  = threadIdx.x;
  const int wave = tid >> 6;
  const int lane = tid & 63;
  const int quad = lane >> 4;
  const int l15  = lane & 15;
  const bool up  = (l15 >= 8);
  const int row  = l15 & 7;
  const int rowbase = blockIdx.x * 8;

  bf8 A[4][5];
#pragma unroll
  for(int q = 0; q < 4; q++){
    const u16* wp = Wc + (u64)(128*q + 16*wave + l15)*160 + quad*8;
#pragma unroll
    for(int kt = 0; kt < 5; kt++) A[q][kt] = *(const bf8*)(wp + kt*32);
  }
  f4 bini[4];
#pragma unroll
  for(int q = 0; q < 4; q++) bini[q] = *(const f4*)(bias + 128*q + 16*wave + quad*4);
  float c0 = 0.f, c1 = 0.f;

  for(int i = tid; i < 2*20*8*8; i += 512) ((u16*)hbT)[i] = 0;
  __syncthreads();
  // stage x(0): threads 0..143, sr=row, sk=comp
  int sr = 0, sk = 0;
  if(tid < 144){ sr = tid/18; sk = tid - 18*sr; }
  if(tid < 144)
    hbT[0][16+(sk>>3)][sr][sk&7] = f2bf(xin[((u64)(rowbase+sr)*512)*18 + sk]);
  __syncthreads();

  const int src = up ? (lane - 8) : lane;
  const int kc  = 2*wave + (quad>>1);
  const int eo  = 4*(quad&1) + (up ? 2 : 0);
  const int jc  = 16*wave + 4*quad + (up ? 2 : 0);

  for(int t = 0; t < 512; t++){
    const int cur = t & 1, nxt = cur ^ 1;
    float xv = 0.f;
    if(tid < 144 && t < 511)
      xv = xin[((u64)(rowbase+sr)*512 + (t+1))*18 + sk];

    bf8 B[5];
#pragma unroll
    for(int kt = 0; kt < 5; kt++) B[kt] = *(const bf8*)&hbT[cur][kt*4+quad][row][0];

    f4 acc[4];
#pragma unroll
    for(int q = 0; q < 4; q++) acc[q] = bini[q];
#pragma unroll
    for(int kt = 0; kt < 5; kt++){
#pragma unroll
      for(int q = 0; q < 4; q++)
        acc[q] = __builtin_amdgcn_mfma_f32_16x16x32_bf16(A[q][kt], B[kt], acc[q], 0,0,0);
    }

    // compact: lanes l15>=8 fetch regs 2,3 from lane-8
    float g0[4], g1[4];
#pragma unroll
    for(int q = 0; q < 4; q++){
      float s2 = __shfl(acc[q][2], src);
      float s3 = __shfl(acc[q][3], src);
      g0[q] = up ? s2 : acc[q][0];
      g1[q] = up ? s3 : acc[q][1];
    }
    float hv0, hv1;
    cell2<false>(g0, g1, c0, c1, hv0, hv1);
    u32 hpair = (u32)f2bf(hv0) | ((u32)f2bf(hv1) << 16);
    *(u32*)&hbT[nxt][kc][row][eo] = hpair;
    *(u32*)(h1out + ((u64)t*512 + rowbase + row)*128 + jc) = hpair;
    if(tid < 144 && t < 511) hbT[nxt][16+(sk>>3)][sr][sk&7] = f2bf(xv);
    bar_lds();
  }
}

// ---------------------------------------------------------------------------
// Layer 1: K=256 = [h2(128) | h1(128)], KT=8. h2 via LDS; h1 straight to
// B-frag registers prefetched one step ahead. Fused FC head.
// ---------------------------------------------------------------------------
__global__ __launch_bounds__(512, 2)
void lstm_l1(const u16* __restrict__ Wc, const float* __restrict__ bias,
             const u16* __restrict__ h1in,    // [512 t][512 row][128] bf16
             const float* __restrict__ Wfc1, const float* __restrict__ bfc1,
             const float* __restrict__ Wfc2, const float* __restrict__ bfc2,
             float* __restrict__ out)         // (512,) f32
{
  __shared__ __align__(16) u16  hbT[2][16][8][8];  // h2 only
  __shared__ __align__(16) float ffin[8][132];     // final h2 f32 for FC head

  const int tid  = threadIdx.x;
  const int wave = tid >> 6;
  const int lane = tid & 63;
  const int quad = lane >> 4;
  const int l15  = lane & 15;
  const bool up  = (l15 >= 8);
  const int row  = l15 & 7;
  const int rowbase = blockIdx.x * 8;

  bf8 A[4][8];
#pragma unroll
  for(int q = 0; q < 4; q++){
    const u16* wp = Wc + (u64)(128*q + 16*wave + l15)*256 + quad*8;
#pragma unroll
    for(int kt = 0; kt < 8; kt++) A[q][kt] = *(const bf8*)(wp + kt*32);
  }
  f4 bini[4];
#pragma unroll
  for(int q = 0; q < 4; q++) bini[q] = *(const f4*)(bias + 128*q + 16*wave + quad*4);
  float c0 = 0.f, c1 = 0.f;

  for(int i = tid; i < 2*16*8*8; i += 512) ((u16*)hbT)[i] = 0;

  // h1 B-frags for t=0 (rows 8..15 duplicate 0..7)
  const u16* h1p = h1in + ((u64)rowbase + row)*128 + 8*quad;
  bf8 h1f[4];
#pragma unroll
  for(int kh = 0; kh < 4; kh++)
    h1f[kh] = *(const bf8*)(h1p + 32*kh);
  __syncthreads();

  const int src = up ? (lane - 8) : lane;
  const int kc  = 2*wave + (quad>>1);
  const int eo  = 4*(quad&1) + (up ? 2 : 0);
  const int jc  = 16*wave + 4*quad + (up ? 2 : 0);

  float hv0 = 0.f, hv1 = 0.f;
  for(int t = 0; t < 512; t++){
    const int cur = t & 1, nxt = cur ^ 1;
    bf8 h1n[4];
    if(t < 511){
#pragma unroll
      for(int kh = 0; kh < 4; kh++)
        h1n[kh] = *(const bf8*)(h1p + ((u64)(t+1))*512*128 + 32*kh);
    }

    bf8 B[4];
#pragma unroll
    for(int kt = 0; kt < 4; kt++) B[kt] = *(const bf8*)&hbT[cur][kt*4+quad][row][0];

    f4 acc[4];
#pragma unroll
    for(int q = 0; q < 4; q++) acc[q] = bini[q];
#pragma unroll
    for(int kt = 0; kt < 4; kt++){
#pragma unroll
      for(int q = 0; q < 4; q++)
        acc[q] = __builtin_amdgcn_mfma_f32_16x16x32_bf16(A[q][kt], B[kt], acc[q], 0,0,0);
    }
#pragma unroll
    for(int kh = 0; kh < 4; kh++){
#pragma unroll
      for(int q = 0; q < 4; q++)
        acc[q] = __builtin_amdgcn_mfma_f32_16x16x32_bf16(A[q][4+kh], h1f[kh], acc[q], 0,0,0);
    }

    float g0[4], g1[4];
#pragma unroll
    for(int q = 0; q < 4; q++){
      float s2 = __shfl(acc[q][2], src);
      float s3 = __shfl(acc[q][3], src);
      g0[q] = up ? s2 : acc[q][0];
      g1[q] = up ? s3 : acc[q][1];
    }
    cell2<false>(g0, g1, c0, c1, hv0, hv1);
    u32 hpair = (u32)f2bf(hv0) | ((u32)f2bf(hv1) << 16);
    *(u32*)&hbT[nxt][kc][row][eo] = hpair;
    bar_lds();
    if(t < 511){
#pragma unroll
      for(int kh = 0; kh < 4; kh++) h1f[kh] = h1n[kh];
    }
  }

  // final h2 (f32) -> LDS for FC head
  ffin[row][jc]   = hv0;
  ffin[row][jc+1] = hv1;
  __syncthreads();

  // FC head: wave w = batch row w; lane u = hidden unit (64 units)
  {
    int r = wave;
    float s = bfc1[lane];
    const float* wrow = Wfc1 + lane*128;
    for(int j = 0; j < 128; j++) s = fmaf(wrow[j], ffin[r][j], s);
    float term = fmaxf(s, 0.f) * Wfc2[lane];
#pragma unroll
    for(int off = 32; off > 0; off >>= 1) term += __shfl_down(term, off);
    if(lane == 0) out[rowbase + r] = sigm_ps((term + bfc2[0]) * LOG2E);
  }
}

// ---------------------------------------------------------------------------
extern "C" void kernel_launch(void* const* d_in, const int* in_sizes, int n_in,
                              void* d_out, int out_size, void* d_ws, size_t ws_size,
                              hipStream_t stream){
  const float* x    = (const float*)d_in[0];
  const float* Wih0 = (const float*)d_in[1];
  const float* Whh0 = (const float*)d_in[2];
  const float* bih0 = (const float*)d_in[3];
  const float* bhh0 = (const float*)d_in[4];
  const float* Wih1 = (const float*)d_in[5];
  const float* Whh1 = (const float*)d_in[6];
  const float* bih1 = (const float*)d_in[7];
  const float* bhh1 = (const float*)d_in[8];
  const float* Wfc1 = (const float*)d_in[9];
  const float* bfc1 = (const float*)d_in[10];
  const float* Wfc2 = (const float*)d_in[11];
  const float* bfc2 = (const float*)d_in[12];

  char* ws = (char*)d_ws;
  u16*   W0c   = (u16*)(ws);                       // 512*160*2 = 163840 B
  u16*   W1c   = (u16*)(ws + 163840);              // 512*256*2 = 262144 B
  float* bias0 = (float*)(ws + 163840 + 262144);   // 2048 B
  float* bias1 = bias0 + 512;                      // 2048 B
  u16*   h1g   = (u16*)(ws + 163840 + 262144 + 4096); // 64 MiB

  prep_kernel<<<dim3(512), dim3(64), 0, stream>>>(Wih0, Whh0, bih0, bhh0,
                                                  Wih1, Whh1, bih1, bhh1,
                                                  W0c, W1c, bias0, bias1);

  lstm_l0<<<dim3(64), dim3(512), 0, stream>>>(W0c, bias0, x, h1g);

  lstm_l1<<<dim3(64), dim3(512), 0, stream>>>(W1c, bias1, h1g,
                                              Wfc1, bfc1, Wfc2, bfc2,
                                              (float*)d_out);
}